// Round 11
// baseline (232.122 us; speedup 1.0000x reference)
//
#include <hip/hip_runtime.h>

#define F_IN 128
#define HID 64
#define CLS 32
#define BCAP 8192   // per-bucket capacity (mean 4096, sigma ~64)

typedef short v8s __attribute__((ext_vector_type(8)));
typedef float f4 __attribute__((ext_vector_type(4)));
typedef float f2 __attribute__((ext_vector_type(2)));

// ---- helpers ----
__device__ __forceinline__ float bflo(unsigned int w) { return __uint_as_float(w << 16); }
__device__ __forceinline__ float bfhi(unsigned int w) { return __uint_as_float(w & 0xFFFF0000u); }
__device__ __forceinline__ unsigned short f2bf(float f) {
    unsigned int u = __float_as_uint(f);
    u += 0x7FFFu + ((u >> 16) & 1u);
    return (unsigned short)(u >> 16);
}
__device__ __forceinline__ unsigned int pack2(float lo, float hi) {
    return (unsigned int)f2bf(lo) | ((unsigned int)f2bf(hi) << 16);
}
__device__ __forceinline__ unsigned char f2fp8(float v) {
    return (unsigned char)(__builtin_amdgcn_cvt_pk_fp8_f32(v, v, 0, false) & 0xFF);
}

// ============ bucket cursor init ============
__global__ __launch_bounds__(512) void k_init(int* __restrict__ bCursor, int nb) {
    int i = threadIdx.x;
    if (i < nb) bCursor[i] = i * BCAP;
}

// ============ bucketed scatter: append (src | local_dst<<17) into bucket windows ============
__global__ __launch_bounds__(256) void k_bscatter(const int* __restrict__ src,
                                                  const int* __restrict__ dst,
                                                  int* __restrict__ bCursor,
                                                  int* __restrict__ bucketed, int E, int nb) {
    __shared__ int h[512];
    __shared__ int chunk[512];
    int tid = threadIdx.x;
    for (int i = tid; i < nb; i += 256) h[i] = 0;
    __syncthreads();

    int e0 = blockIdx.x * 2048;
    int myRec[8], myB[8], myRank[8];
#pragma unroll
    for (int k = 0; k < 8; ++k) {
        int e = e0 + k * 256 + tid;
        if (e < E) {
            int d = dst[e];
            myB[k] = d >> 8;
            myRec[k] = src[e] | ((d & 255) << 17);
            myRank[k] = atomicAdd(&h[myB[k]], 1);
        } else {
            myB[k] = -1;
        }
    }
    __syncthreads();
    for (int i = tid; i < nb; i += 256)
        chunk[i] = h[i] ? atomicAdd(&bCursor[i], h[i]) : 0;
    __syncthreads();
#pragma unroll
    for (int k = 0; k < 8; ++k) {
        if (myB[k] >= 0) bucketed[chunk[myB[k]] + myRank[k]] = myRec[k];
    }
}

// ============ per-bucket CSR: count -> scan -> pk/dinv + node-sorted fill ============
// pk[node] = csr_offset | (cnt << 22)   (offset < 3.2M < 2^22, cnt < 1024)
__global__ __launch_bounds__(256) void k_csr(const int* __restrict__ bCursor,
                                             const int* __restrict__ bucketed,
                                             int* __restrict__ pk,
                                             float* __restrict__ dinv, int* __restrict__ csr,
                                             int n) {
    __shared__ int cnt[256];
    __shared__ int s[256];
    __shared__ int cur[256];
    int b = blockIdx.x;
    int node0 = b << 8;
    int tid = threadIdx.x;
    int node = node0 + tid;
    cnt[tid] = 0;
    __syncthreads();
    int p0 = b * BCAP, p1 = bCursor[b];
    for (int p = p0 + tid; p < p1; p += 256) {
        int rec = bucketed[p];
        atomicAdd(&cnt[rec >> 17], 1);
    }
    __syncthreads();
    int v = cnt[tid];
    s[tid] = v;
    __syncthreads();
    for (int off = 1; off < 256; off <<= 1) {
        int t = (tid >= off) ? s[tid - off] : 0;
        __syncthreads();
        s[tid] += t;
        __syncthreads();
    }
    int myoff = p0 + s[tid] - v;
    cur[tid] = myoff;
    if (node < n) {
        pk[node] = myoff | (v << 22);
        dinv[node] = rsqrtf((float)(v + 1));
    }
    __syncthreads();
    for (int p = p0 + tid; p < p1; p += 256) {
        int rec = bucketed[p];
        int q = atomicAdd(&cur[rec >> 17], 1);
        csr[q] = rec & 0x1FFFF;
    }
}

// ============ MFMA GEMM1: x[N,128](f32) @ W1[128,64] * dinv[r] -> fp8 y[N,64] ============
__global__ __launch_bounds__(256) void k_gemm1(const float* __restrict__ x,
                                               const float* __restrict__ W,
                                               const float* __restrict__ dinv,
                                               unsigned char* __restrict__ y, int n) {
    __shared__ unsigned short Wt[HID * 136];
    int tid = threadIdx.x;
    for (int i = tid; i < F_IN * HID; i += 256) {
        int k = i >> 6, nn = i & 63;
        Wt[nn * 136 + k] = f2bf(W[i]);
    }
    __syncthreads();

    int lane = tid & 63;
    int quad = lane >> 4, c = lane & 15;
    int nstripes = (n + 31) >> 5;
    int stripe = blockIdx.x * 4 + (tid >> 6);
    if (stripe >= nstripes) return;
    int row0 = stripe << 5;

    f4 acc[2][4] = {};
    union { unsigned int u[4]; v8s v; } au;

#pragma unroll
    for (int ks = 0; ks < 4; ++ks) {
        int k0 = ks * 32 + quad * 8;
        v8s a[2];
#pragma unroll
        for (int mt = 0; mt < 2; ++mt) {
            int row = row0 + mt * 16 + c;
            if (row >= n) row = n - 1;
            const float* xp = x + (size_t)row * F_IN + k0;
            float4 lo = *(const float4*)xp;
            float4 hi = *(const float4*)(xp + 4);
            au.u[0] = pack2(lo.x, lo.y);
            au.u[1] = pack2(lo.z, lo.w);
            au.u[2] = pack2(hi.x, hi.y);
            au.u[3] = pack2(hi.z, hi.w);
            a[mt] = au.v;
        }
#pragma unroll
        for (int nt = 0; nt < 4; ++nt) {
            v8s b = *(const v8s*)&Wt[(nt * 16 + c) * 136 + k0];
            acc[0][nt] = __builtin_amdgcn_mfma_f32_16x16x32_bf16(a[0], b, acc[0][nt], 0, 0, 0);
            acc[1][nt] = __builtin_amdgcn_mfma_f32_16x16x32_bf16(a[1], b, acc[1][nt], 0, 0, 0);
        }
    }

#pragma unroll
    for (int mt = 0; mt < 2; ++mt)
#pragma unroll
        for (int reg = 0; reg < 4; ++reg) {
            int row = row0 + mt * 16 + quad * 4 + reg;
            if (row < n) {
                float dd = dinv[row];
#pragma unroll
                for (int nt = 0; nt < 4; ++nt)
                    y[(size_t)row * HID + nt * 16 + c] = f2fp8(acc[mt][nt][reg] * dd);
            }
        }
}

// ============ fused gather64 + GEMM2 ============
// Each block: 128 nodes. Phase 1: 16 groups x 8 nodes gather fp8 rows (4-way MLP),
// h1 = relu(sum*dd + b1) -> LDS tile (bf16, stride 72). Phase 2: 4 waves MFMA
// stripes of 32 rows from LDS vs W2, scale by dinv[row], store bf16 hw.
__global__ __launch_bounds__(256) void k_gg2(const int* __restrict__ pk,
                                             const int* __restrict__ csr,
                                             const unsigned char* __restrict__ xw8,
                                             const float* __restrict__ b1,
                                             const float* __restrict__ W2,
                                             const float* __restrict__ dinv,
                                             unsigned short* __restrict__ y, int n) {
    __shared__ unsigned short Ht[128 * 72];   // 18.4 KB h1 tile
    __shared__ unsigned short Wt[CLS * 72];   // 4.6 KB W2^T
    int tid = threadIdx.x;
    for (int i = tid; i < HID * CLS; i += 256) {
        int k = i >> 5, nn = i & 31;
        Wt[nn * 72 + k] = f2bf(W2[i]);
    }

    int node0 = blockIdx.x * 128;
    int g = tid >> 4;    // group 0..15
    int l = tid & 15;    // 4B chunk = fp8 cols 4l..4l+3

    // ---- phase 1: gather 8 nodes per group ----
    for (int j = 0; j < 8; ++j) {
        int local = g * 8 + j;
        int node = node0 + local;
        if (node >= n) break;
        unsigned int pv = (unsigned int)pk[node];
        int p0 = pv & 0x3FFFFF;
        int cntv = (int)(pv >> 22);
        int p1 = p0 + cntv;
        float dd = rsqrtf((float)(cntv + 1));
        unsigned int sw = *(const unsigned int*)(xw8 + (size_t)node * HID + l * 4);

        f2 A0 = {0.f, 0.f}, A1 = A0, B0 = A0, B1 = A0, C0 = A0, C1 = A0, D0 = A0, D1 = A0;
        int p = p0;
        for (; p + 3 < p1; p += 4) {
            int s0 = csr[p], s1 = csr[p + 1], s2 = csr[p + 2], s3 = csr[p + 3];
            unsigned int w0 = *(const unsigned int*)(xw8 + (size_t)s0 * HID + l * 4);
            unsigned int w1 = *(const unsigned int*)(xw8 + (size_t)s1 * HID + l * 4);
            unsigned int w2 = *(const unsigned int*)(xw8 + (size_t)s2 * HID + l * 4);
            unsigned int w3 = *(const unsigned int*)(xw8 + (size_t)s3 * HID + l * 4);
            A0 += __builtin_amdgcn_cvt_pk_f32_fp8(w0, false);
            A1 += __builtin_amdgcn_cvt_pk_f32_fp8(w0, true);
            B0 += __builtin_amdgcn_cvt_pk_f32_fp8(w1, false);
            B1 += __builtin_amdgcn_cvt_pk_f32_fp8(w1, true);
            C0 += __builtin_amdgcn_cvt_pk_f32_fp8(w2, false);
            C1 += __builtin_amdgcn_cvt_pk_f32_fp8(w2, true);
            D0 += __builtin_amdgcn_cvt_pk_f32_fp8(w3, false);
            D1 += __builtin_amdgcn_cvt_pk_f32_fp8(w3, true);
        }
        for (; p < p1; ++p) {
            int s = csr[p];
            unsigned int w = *(const unsigned int*)(xw8 + (size_t)s * HID + l * 4);
            A0 += __builtin_amdgcn_cvt_pk_f32_fp8(w, false);
            A1 += __builtin_amdgcn_cvt_pk_f32_fp8(w, true);
        }
        A0 += B0; C0 += D0; A0 += C0;
        A1 += B1; C1 += D1; A1 += C1;
        A0 += __builtin_amdgcn_cvt_pk_f32_fp8(sw, false);
        A1 += __builtin_amdgcn_cvt_pk_f32_fp8(sw, true);

        float4 bb = *(const float4*)(b1 + l * 4);
        float v0 = fmaxf(A0.x * dd + bb.x, 0.f);
        float v1 = fmaxf(A0.y * dd + bb.y, 0.f);
        float v2 = fmaxf(A1.x * dd + bb.z, 0.f);
        float v3 = fmaxf(A1.y * dd + bb.w, 0.f);
        uint2 o;
        o.x = pack2(v0, v1);
        o.y = pack2(v2, v3);
        *(uint2*)&Ht[local * 72 + l * 4] = o;
    }
    __syncthreads();

    // ---- phase 2: MFMA gemm2 from LDS ----
    int lane = tid & 63;
    int quad = lane >> 4, c = lane & 15;
    int w = tid >> 6;       // wave 0..3 -> local rows w*32..w*32+31
    int row0 = w * 32;

    f4 acc[2][2] = {};
#pragma unroll
    for (int ks = 0; ks < 2; ++ks) {
        int k0 = ks * 32 + quad * 8;
        v8s a[2];
#pragma unroll
        for (int mt = 0; mt < 2; ++mt) {
            int lrow = row0 + mt * 16 + c;
            a[mt] = *(const v8s*)&Ht[lrow * 72 + k0];
        }
#pragma unroll
        for (int nt = 0; nt < 2; ++nt) {
            v8s bfr = *(const v8s*)&Wt[(nt * 16 + c) * 72 + k0];
            acc[0][nt] = __builtin_amdgcn_mfma_f32_16x16x32_bf16(a[0], bfr, acc[0][nt], 0, 0, 0);
            acc[1][nt] = __builtin_amdgcn_mfma_f32_16x16x32_bf16(a[1], bfr, acc[1][nt], 0, 0, 0);
        }
    }

#pragma unroll
    for (int mt = 0; mt < 2; ++mt)
#pragma unroll
        for (int reg = 0; reg < 4; ++reg) {
            int node = node0 + row0 + mt * 16 + quad * 4 + reg;
            if (node < n) {
                float dd2 = dinv[node];
#pragma unroll
                for (int nt = 0; nt < 2; ++nt)
                    y[(size_t)node * CLS + nt * 16 + c] = f2bf(acc[mt][nt][reg] * dd2);
            }
        }
}

// ============ gather width 32 (bf16 rows) + log_softmax: group-per-node, 4-way MLP ============
__global__ __launch_bounds__(256) void k_gather32_lsm(const int* __restrict__ pk,
                                                      const int* __restrict__ csr,
                                                      const unsigned short* __restrict__ hwb,
                                                      const float* __restrict__ b,
                                                      float* __restrict__ out, int n) {
    int node = blockIdx.x * 16 + (threadIdx.x >> 4);
    if (node >= n) return;
    int l = threadIdx.x & 15;    // cols 2l, 2l+1
    unsigned int pv = (unsigned int)pk[node];
    int p0 = pv & 0x3FFFFF;
    int cntv = (int)(pv >> 22);
    int p1 = p0 + cntv;
    float dd = rsqrtf((float)(cntv + 1));
    unsigned int sw = *(const unsigned int*)(hwb + (size_t)node * CLS + l * 2);

    float A0 = 0.f, A1 = 0.f, B0 = 0.f, B1 = 0.f, C0 = 0.f, C1 = 0.f, D0 = 0.f, D1 = 0.f;
    int p = p0;
    for (; p + 3 < p1; p += 4) {
        int s0 = csr[p], s1 = csr[p + 1], s2 = csr[p + 2], s3 = csr[p + 3];
        unsigned int w0 = *(const unsigned int*)(hwb + (size_t)s0 * CLS + l * 2);
        unsigned int w1 = *(const unsigned int*)(hwb + (size_t)s1 * CLS + l * 2);
        unsigned int w2 = *(const unsigned int*)(hwb + (size_t)s2 * CLS + l * 2);
        unsigned int w3 = *(const unsigned int*)(hwb + (size_t)s3 * CLS + l * 2);
        A0 += bflo(w0); A1 += bfhi(w0);
        B0 += bflo(w1); B1 += bfhi(w1);
        C0 += bflo(w2); C1 += bfhi(w2);
        D0 += bflo(w3); D1 += bfhi(w3);
    }
    for (; p < p1; ++p) {
        int s = csr[p];
        unsigned int w = *(const unsigned int*)(hwb + (size_t)s * CLS + l * 2);
        A0 += bflo(w); A1 += bfhi(w);
    }
    A0 += B0; C0 += D0; A0 += C0;
    A1 += B1; C1 += D1; A1 += C1;

    float v0 = (A0 + bflo(sw)) * dd + b[l * 2];
    float v1 = (A1 + bfhi(sw)) * dd + b[l * 2 + 1];

    float m = fmaxf(v0, v1);
    m = fmaxf(m, __shfl_xor(m, 1));
    m = fmaxf(m, __shfl_xor(m, 2));
    m = fmaxf(m, __shfl_xor(m, 4));
    m = fmaxf(m, __shfl_xor(m, 8));
    float s = __expf(v0 - m) + __expf(v1 - m);
    s += __shfl_xor(s, 1);
    s += __shfl_xor(s, 2);
    s += __shfl_xor(s, 4);
    s += __shfl_xor(s, 8);
    float ls = m + __logf(s);
    float2 o;
    o.x = v0 - ls;
    o.y = v1 - ls;
    *(float2*)(out + (size_t)node * CLS + l * 2) = o;
}

extern "C" void kernel_launch(void* const* d_in, const int* in_sizes, int n_in,
                              void* d_out, int out_size, void* d_ws, size_t ws_size,
                              hipStream_t stream) {
    const float* x  = (const float*)d_in[0];
    const int* edge = (const int*)d_in[1];
    const float* W1 = (const float*)d_in[2];
    const float* b1 = (const float*)d_in[3];
    const float* W2 = (const float*)d_in[4];
    const float* b2 = (const float*)d_in[5];
    float* out = (float*)d_out;

    int N = in_sizes[0] / F_IN;
    int E = in_sizes[1] / 2;
    const int* src = edge;
    const int* dst = edge + E;
    int NB = (N + 255) >> 8;   // 391 buckets

    // workspace layout
    float* dinv    = (float*)d_ws;                        // N f32
    int* pk        = (int*)(dinv + N);                    // N (off | cnt<<22)
    int* bCursor   = pk + N;                              // 512
    int* csr       = bCursor + 512;                       // NB*BCAP (windowed)
    int* bucketed  = csr + (size_t)NB * BCAP;             // NB*BCAP (windowed)
    unsigned char* bufA = (unsigned char*)(bucketed + (size_t)NB * BCAP);  // N*64 B fp8 xw
    unsigned short* bufC = (unsigned short*)(bufA + (size_t)N * HID);      // N*32 bf16 hw

    // ---- bucketed CSR build ----
    k_init<<<1, 512, 0, stream>>>(bCursor, NB);
    k_bscatter<<<(E + 2047) / 2048, 256, 0, stream>>>(src, dst, bCursor, bucketed, E, NB);
    k_csr<<<NB, 256, 0, stream>>>(bCursor, bucketed, pk, dinv, csr, N);

    int nstripes = (N + 31) >> 5;
    int gemmBlocks = (nstripes + 3) / 4;

    // ---- layer 1 GEMM (fp8 xw table) ----
    k_gemm1<<<gemmBlocks, 256, 0, stream>>>(x, W1, dinv, bufA, N);

    // ---- fused: gather layer-1 + GEMM2 -> hw ----
    k_gg2<<<(N + 127) / 128, 256, 0, stream>>>(pk, csr, bufA, b1, W2, dinv, bufC, N);

    // ---- layer 2 gather + log_softmax ----
    k_gather32_lsm<<<(N + 15) / 16, 256, 0, stream>>>(pk, csr, bufC, b2, out, N);
}

// Round 12
// 218.369 us; speedup vs baseline: 1.0630x; 1.0630x over previous
//
#include <hip/hip_runtime.h>

#define F_IN 128
#define HID 64
#define CLS 32
#define BCAP 8192   // per-bucket capacity (mean 4096, sigma ~64 -> >60 sigma headroom)

typedef short v8s __attribute__((ext_vector_type(8)));
typedef float f4 __attribute__((ext_vector_type(4)));
typedef float f2 __attribute__((ext_vector_type(2)));

// ---- helpers ----
__device__ __forceinline__ float bflo(unsigned int w) { return __uint_as_float(w << 16); }
__device__ __forceinline__ float bfhi(unsigned int w) { return __uint_as_float(w & 0xFFFF0000u); }
__device__ __forceinline__ unsigned short f2bf(float f) {
    unsigned int u = __float_as_uint(f);
    u += 0x7FFFu + ((u >> 16) & 1u);
    return (unsigned short)(u >> 16);
}
__device__ __forceinline__ unsigned int pack2(float lo, float hi) {
    return (unsigned int)f2bf(lo) | ((unsigned int)f2bf(hi) << 16);
}
__device__ __forceinline__ unsigned int relu2(unsigned int w) {
    unsigned int lo = (w & 0x8000u) ? 0u : (w & 0xFFFFu);
    unsigned int hi = (w & 0x80000000u) ? 0u : (w & 0xFFFF0000u);
    return lo | hi;
}
__device__ __forceinline__ unsigned char f2fp8(float v) {
    return (unsigned char)(__builtin_amdgcn_cvt_pk_fp8_f32(v, v, 0, false) & 0xFF);
}

// ============ bucket cursor init ============
__global__ __launch_bounds__(512) void k_init(int* __restrict__ bCursor, int nb) {
    int i = threadIdx.x;
    if (i < nb) bCursor[i] = i * BCAP;
}

// ============ bucketed scatter: append (src | local_dst<<17) into bucket windows ============
__global__ __launch_bounds__(256) void k_bscatter(const int* __restrict__ src,
                                                  const int* __restrict__ dst,
                                                  int* __restrict__ bCursor,
                                                  int* __restrict__ bucketed, int E, int nb) {
    __shared__ int h[512];
    __shared__ int chunk[512];
    int tid = threadIdx.x;
    for (int i = tid; i < nb; i += 256) h[i] = 0;
    __syncthreads();

    int e0 = blockIdx.x * 2048;
    int myRec[8], myB[8], myRank[8];
#pragma unroll
    for (int k = 0; k < 8; ++k) {
        int e = e0 + k * 256 + tid;
        if (e < E) {
            int d = dst[e];
            myB[k] = d >> 8;
            myRec[k] = src[e] | ((d & 255) << 17);
            myRank[k] = atomicAdd(&h[myB[k]], 1);
        } else {
            myB[k] = -1;
        }
    }
    __syncthreads();
    for (int i = tid; i < nb; i += 256)
        chunk[i] = h[i] ? atomicAdd(&bCursor[i], h[i]) : 0;
    __syncthreads();
#pragma unroll
    for (int k = 0; k < 8; ++k) {
        if (myB[k] >= 0) bucketed[chunk[myB[k]] + myRank[k]] = myRec[k];
    }
}

// ============ per-bucket CSR: count -> scan -> pk/dinv + node-sorted fill ============
// pk[node] = csr_offset | (cnt << 22)   (offset < 3.2M < 2^22, cnt < 1024)
__global__ __launch_bounds__(256) void k_csr(const int* __restrict__ bCursor,
                                             const int* __restrict__ bucketed,
                                             int* __restrict__ pk,
                                             float* __restrict__ dinv, int* __restrict__ csr,
                                             int n) {
    __shared__ int cnt[256];
    __shared__ int s[256];
    __shared__ int cur[256];
    int b = blockIdx.x;
    int node0 = b << 8;
    int tid = threadIdx.x;
    int node = node0 + tid;
    cnt[tid] = 0;
    __syncthreads();
    int p0 = b * BCAP, p1 = bCursor[b];
    for (int p = p0 + tid; p < p1; p += 256) {
        int rec = bucketed[p];
        atomicAdd(&cnt[rec >> 17], 1);
    }
    __syncthreads();
    int v = cnt[tid];
    s[tid] = v;
    __syncthreads();
    for (int off = 1; off < 256; off <<= 1) {
        int t = (tid >= off) ? s[tid - off] : 0;
        __syncthreads();
        s[tid] += t;
        __syncthreads();
    }
    int myoff = p0 + s[tid] - v;
    cur[tid] = myoff;
    if (node < n) {
        pk[node] = myoff | (v << 22);
        dinv[node] = rsqrtf((float)(v + 1));
    }
    __syncthreads();
    for (int p = p0 + tid; p < p1; p += 256) {
        int rec = bucketed[p];
        int q = atomicAdd(&cur[rec >> 17], 1);
        csr[q] = rec & 0x1FFFF;
    }
}

// ============ MFMA GEMM1: x[N,128](f32) @ W1[128,64] * dinv[r] -> fp8 y[N,64] ============
__global__ __launch_bounds__(256) void k_gemm1(const float* __restrict__ x,
                                               const float* __restrict__ W,
                                               const float* __restrict__ dinv,
                                               unsigned char* __restrict__ y, int n) {
    __shared__ unsigned short Wt[HID * 136];
    int tid = threadIdx.x;
    for (int i = tid; i < F_IN * HID; i += 256) {
        int k = i >> 6, nn = i & 63;
        Wt[nn * 136 + k] = f2bf(W[i]);
    }
    __syncthreads();

    int lane = tid & 63;
    int quad = lane >> 4, c = lane & 15;
    int nstripes = (n + 31) >> 5;
    int stripe = blockIdx.x * 4 + (tid >> 6);
    if (stripe >= nstripes) return;
    int row0 = stripe << 5;

    f4 acc[2][4] = {};
    union { unsigned int u[4]; v8s v; } au;

#pragma unroll
    for (int ks = 0; ks < 4; ++ks) {
        int k0 = ks * 32 + quad * 8;
        v8s a[2];
#pragma unroll
        for (int mt = 0; mt < 2; ++mt) {
            int row = row0 + mt * 16 + c;
            if (row >= n) row = n - 1;
            const float* xp = x + (size_t)row * F_IN + k0;
            float4 lo = *(const float4*)xp;
            float4 hi = *(const float4*)(xp + 4);
            au.u[0] = pack2(lo.x, lo.y);
            au.u[1] = pack2(lo.z, lo.w);
            au.u[2] = pack2(hi.x, hi.y);
            au.u[3] = pack2(hi.z, hi.w);
            a[mt] = au.v;
        }
#pragma unroll
        for (int nt = 0; nt < 4; ++nt) {
            v8s b = *(const v8s*)&Wt[(nt * 16 + c) * 136 + k0];
            acc[0][nt] = __builtin_amdgcn_mfma_f32_16x16x32_bf16(a[0], b, acc[0][nt], 0, 0, 0);
            acc[1][nt] = __builtin_amdgcn_mfma_f32_16x16x32_bf16(a[1], b, acc[1][nt], 0, 0, 0);
        }
    }

#pragma unroll
    for (int mt = 0; mt < 2; ++mt)
#pragma unroll
        for (int reg = 0; reg < 4; ++reg) {
            int row = row0 + mt * 16 + quad * 4 + reg;
            if (row < n) {
                float dd = dinv[row];
#pragma unroll
                for (int nt = 0; nt < 4; ++nt)
                    y[(size_t)row * HID + nt * 16 + c] = f2fp8(acc[mt][nt][reg] * dd);
            }
        }
}

// ============ MFMA GEMM2: relu(bf16 h)[N,64] @ W2[64,32] * dinv[r] -> bf16 y[N,32] ============
__global__ __launch_bounds__(256) void k_gemm2(const unsigned short* __restrict__ hb,
                                               const float* __restrict__ W,
                                               const float* __restrict__ dinv,
                                               unsigned short* __restrict__ y, int n) {
    __shared__ unsigned short Wt[CLS * 72];
    int tid = threadIdx.x;
    for (int i = tid; i < HID * CLS; i += 256) {
        int k = i >> 5, nn = i & 31;
        Wt[nn * 72 + k] = f2bf(W[i]);
    }
    __syncthreads();

    int lane = tid & 63;
    int quad = lane >> 4, c = lane & 15;
    int nstripes = (n + 31) >> 5;
    int stripe = blockIdx.x * 4 + (tid >> 6);
    if (stripe >= nstripes) return;
    int row0 = stripe << 5;

    f4 acc[2][2] = {};
    union { unsigned int u[4]; v8s v; } au;

#pragma unroll
    for (int ks = 0; ks < 2; ++ks) {
        int k0 = ks * 32 + quad * 8;
        v8s a[2];
#pragma unroll
        for (int mt = 0; mt < 2; ++mt) {
            int row = row0 + mt * 16 + c;
            if (row >= n) row = n - 1;
            uint4 w = *(const uint4*)(hb + (size_t)row * HID + k0);
            au.u[0] = relu2(w.x);
            au.u[1] = relu2(w.y);
            au.u[2] = relu2(w.z);
            au.u[3] = relu2(w.w);
            a[mt] = au.v;
        }
#pragma unroll
        for (int nt = 0; nt < 2; ++nt) {
            v8s b = *(const v8s*)&Wt[(nt * 16 + c) * 72 + k0];
            acc[0][nt] = __builtin_amdgcn_mfma_f32_16x16x32_bf16(a[0], b, acc[0][nt], 0, 0, 0);
            acc[1][nt] = __builtin_amdgcn_mfma_f32_16x16x32_bf16(a[1], b, acc[1][nt], 0, 0, 0);
        }
    }

#pragma unroll
    for (int mt = 0; mt < 2; ++mt)
#pragma unroll
        for (int reg = 0; reg < 4; ++reg) {
            int row = row0 + mt * 16 + quad * 4 + reg;
            if (row < n) {
                float dd = dinv[row];
#pragma unroll
                for (int nt = 0; nt < 2; ++nt)
                    y[(size_t)row * CLS + nt * 16 + c] = f2bf(acc[mt][nt][reg] * dd);
            }
        }
}

// ============ gather width 64 (fp8 rows, 64B): one node per 16-lane group, 4-way MLP ============
__global__ __launch_bounds__(256) void k_gather64(const int* __restrict__ pk,
                                                  const int* __restrict__ csr,
                                                  const unsigned char* __restrict__ xw8,
                                                  const float* __restrict__ b,
                                                  unsigned short* __restrict__ hb, int n) {
    int node = blockIdx.x * 16 + (threadIdx.x >> 4);
    if (node >= n) return;
    int l = threadIdx.x & 15;    // 4B chunk = cols 4l..4l+3
    unsigned int pv = (unsigned int)pk[node];
    int p0 = pv & 0x3FFFFF;
    int cntv = (int)(pv >> 22);
    int p1 = p0 + cntv;
    float dd = rsqrtf((float)(cntv + 1));
    unsigned int sw = *(const unsigned int*)(xw8 + (size_t)node * HID + l * 4);

    f2 A0 = {0.f, 0.f}, A1 = A0, B0 = A0, B1 = A0, C0 = A0, C1 = A0, D0 = A0, D1 = A0;
    int p = p0;
    for (; p + 3 < p1; p += 4) {
        int s0 = csr[p], s1 = csr[p + 1], s2 = csr[p + 2], s3 = csr[p + 3];
        unsigned int w0 = *(const unsigned int*)(xw8 + (size_t)s0 * HID + l * 4);
        unsigned int w1 = *(const unsigned int*)(xw8 + (size_t)s1 * HID + l * 4);
        unsigned int w2 = *(const unsigned int*)(xw8 + (size_t)s2 * HID + l * 4);
        unsigned int w3 = *(const unsigned int*)(xw8 + (size_t)s3 * HID + l * 4);
        A0 += __builtin_amdgcn_cvt_pk_f32_fp8(w0, false);
        A1 += __builtin_amdgcn_cvt_pk_f32_fp8(w0, true);
        B0 += __builtin_amdgcn_cvt_pk_f32_fp8(w1, false);
        B1 += __builtin_amdgcn_cvt_pk_f32_fp8(w1, true);
        C0 += __builtin_amdgcn_cvt_pk_f32_fp8(w2, false);
        C1 += __builtin_amdgcn_cvt_pk_f32_fp8(w2, true);
        D0 += __builtin_amdgcn_cvt_pk_f32_fp8(w3, false);
        D1 += __builtin_amdgcn_cvt_pk_f32_fp8(w3, true);
    }
    for (; p < p1; ++p) {
        int s = csr[p];
        unsigned int w = *(const unsigned int*)(xw8 + (size_t)s * HID + l * 4);
        A0 += __builtin_amdgcn_cvt_pk_f32_fp8(w, false);
        A1 += __builtin_amdgcn_cvt_pk_f32_fp8(w, true);
    }
    A0 += B0; C0 += D0; A0 += C0;
    A1 += B1; C1 += D1; A1 += C1;

    A0 += __builtin_amdgcn_cvt_pk_f32_fp8(sw, false);
    A1 += __builtin_amdgcn_cvt_pk_f32_fp8(sw, true);
    float4 bb = *(const float4*)(b + l * 4);
    uint2 o;
    o.x = pack2(A0.x * dd + bb.x, A0.y * dd + bb.y);
    o.y = pack2(A1.x * dd + bb.z, A1.y * dd + bb.w);
    *(uint2*)(hb + (size_t)node * HID + l * 4) = o;
}

// ============ gather width 32 (bf16 rows) + log_softmax: group-per-node, 4-way MLP ============
__global__ __launch_bounds__(256) void k_gather32_lsm(const int* __restrict__ pk,
                                                      const int* __restrict__ csr,
                                                      const unsigned short* __restrict__ hwb,
                                                      const float* __restrict__ b,
                                                      float* __restrict__ out, int n) {
    int node = blockIdx.x * 16 + (threadIdx.x >> 4);
    if (node >= n) return;
    int l = threadIdx.x & 15;    // cols 2l, 2l+1
    unsigned int pv = (unsigned int)pk[node];
    int p0 = pv & 0x3FFFFF;
    int cntv = (int)(pv >> 22);
    int p1 = p0 + cntv;
    float dd = rsqrtf((float)(cntv + 1));
    unsigned int sw = *(const unsigned int*)(hwb + (size_t)node * CLS + l * 2);

    float A0 = 0.f, A1 = 0.f, B0 = 0.f, B1 = 0.f, C0 = 0.f, C1 = 0.f, D0 = 0.f, D1 = 0.f;
    int p = p0;
    for (; p + 3 < p1; p += 4) {
        int s0 = csr[p], s1 = csr[p + 1], s2 = csr[p + 2], s3 = csr[p + 3];
        unsigned int w0 = *(const unsigned int*)(hwb + (size_t)s0 * CLS + l * 2);
        unsigned int w1 = *(const unsigned int*)(hwb + (size_t)s1 * CLS + l * 2);
        unsigned int w2 = *(const unsigned int*)(hwb + (size_t)s2 * CLS + l * 2);
        unsigned int w3 = *(const unsigned int*)(hwb + (size_t)s3 * CLS + l * 2);
        A0 += bflo(w0); A1 += bfhi(w0);
        B0 += bflo(w1); B1 += bfhi(w1);
        C0 += bflo(w2); C1 += bfhi(w2);
        D0 += bflo(w3); D1 += bfhi(w3);
    }
    for (; p < p1; ++p) {
        int s = csr[p];
        unsigned int w = *(const unsigned int*)(hwb + (size_t)s * CLS + l * 2);
        A0 += bflo(w); A1 += bfhi(w);
    }
    A0 += B0; C0 += D0; A0 += C0;
    A1 += B1; C1 += D1; A1 += C1;

    float v0 = (A0 + bflo(sw)) * dd + b[l * 2];
    float v1 = (A1 + bfhi(sw)) * dd + b[l * 2 + 1];

    float m = fmaxf(v0, v1);
    m = fmaxf(m, __shfl_xor(m, 1));
    m = fmaxf(m, __shfl_xor(m, 2));
    m = fmaxf(m, __shfl_xor(m, 4));
    m = fmaxf(m, __shfl_xor(m, 8));
    float s = __expf(v0 - m) + __expf(v1 - m);
    s += __shfl_xor(s, 1);
    s += __shfl_xor(s, 2);
    s += __shfl_xor(s, 4);
    s += __shfl_xor(s, 8);
    float ls = m + __logf(s);
    float2 o;
    o.x = v0 - ls;
    o.y = v1 - ls;
    *(float2*)(out + (size_t)node * CLS + l * 2) = o;
}

extern "C" void kernel_launch(void* const* d_in, const int* in_sizes, int n_in,
                              void* d_out, int out_size, void* d_ws, size_t ws_size,
                              hipStream_t stream) {
    const float* x  = (const float*)d_in[0];
    const int* edge = (const int*)d_in[1];
    const float* W1 = (const float*)d_in[2];
    const float* b1 = (const float*)d_in[3];
    const float* W2 = (const float*)d_in[4];
    const float* b2 = (const float*)d_in[5];
    float* out = (float*)d_out;

    int N = in_sizes[0] / F_IN;
    int E = in_sizes[1] / 2;
    const int* src = edge;
    const int* dst = edge + E;
    int NB = (N + 255) >> 8;   // 391 buckets

    // workspace layout
    float* dinv    = (float*)d_ws;                        // N f32 (gemm epilogues)
    int* pk        = (int*)(dinv + N);                    // N (off | cnt<<22)
    int* bCursor   = pk + N;                              // 512
    int* csr       = bCursor + 512;                       // NB*BCAP (windowed)
    int* bucketed  = csr + (size_t)NB * BCAP;             // NB*BCAP (windowed)
    unsigned char* bufA = (unsigned char*)(bucketed + (size_t)NB * BCAP);  // N*64 B fp8 xw, later bf16 hw (N*32*2B)
    unsigned short* bufB = (unsigned short*)(bufA + (size_t)N * HID);      // N*64 bf16 h1

    // ---- bucketed CSR build ----
    k_init<<<1, 512, 0, stream>>>(bCursor, NB);
    k_bscatter<<<(E + 2047) / 2048, 256, 0, stream>>>(src, dst, bCursor, bucketed, E, NB);
    k_csr<<<NB, 256, 0, stream>>>(bCursor, bucketed, pk, dinv, csr, N);

    int nstripes = (N + 31) >> 5;
    int gemmBlocks = (nstripes + 3) / 4;
    int gatherBlocks = (N + 15) / 16;

    // ---- layer 1 (fp8 xw table) ----
    k_gemm1<<<gemmBlocks, 256, 0, stream>>>(x, W1, dinv, bufA, N);
    k_gather64<<<gatherBlocks, 256, 0, stream>>>(pk, csr, bufA, b1, bufB, N);

    // ---- layer 2 (bf16 hw table, aliases bufA) ----
    k_gemm2<<<gemmBlocks, 256, 0, stream>>>(bufB, W2, dinv, (unsigned short*)bufA, N);
    k_gather32_lsm<<<gatherBlocks, 256, 0, stream>>>(pk, csr, (unsigned short*)bufA, b2, out, N);
}

// Round 13
// 215.837 us; speedup vs baseline: 1.0754x; 1.0117x over previous
//
#include <hip/hip_runtime.h>

#define F_IN 128
#define HID 64
#define CLS 32
#define BCAP 8192   // per-bucket capacity (mean 4096, sigma ~64 -> >60 sigma headroom)

typedef short v8s __attribute__((ext_vector_type(8)));
typedef float f4 __attribute__((ext_vector_type(4)));
typedef float f2 __attribute__((ext_vector_type(2)));

// ---- helpers ----
__device__ __forceinline__ float bflo(unsigned int w) { return __uint_as_float(w << 16); }
__device__ __forceinline__ float bfhi(unsigned int w) { return __uint_as_float(w & 0xFFFF0000u); }
__device__ __forceinline__ unsigned short f2bf(float f) {
    unsigned int u = __float_as_uint(f);
    u += 0x7FFFu + ((u >> 16) & 1u);
    return (unsigned short)(u >> 16);
}
__device__ __forceinline__ unsigned int pack2(float lo, float hi) {
    return (unsigned int)f2bf(lo) | ((unsigned int)f2bf(hi) << 16);
}
__device__ __forceinline__ unsigned int relu2(unsigned int w) {
    unsigned int lo = (w & 0x8000u) ? 0u : (w & 0xFFFFu);
    unsigned int hi = (w & 0x80000000u) ? 0u : (w & 0xFFFF0000u);
    return lo | hi;
}
__device__ __forceinline__ unsigned char f2fp8(float v) {
    return (unsigned char)(__builtin_amdgcn_cvt_pk_fp8_f32(v, v, 0, false) & 0xFF);
}

// ============ bucket cursor init ============
__global__ __launch_bounds__(512) void k_init(int* __restrict__ bCursor, int nb) {
    int i = threadIdx.x;
    if (i < nb) bCursor[i] = i * BCAP;
}

// ============ bucketed scatter: append (src | local_dst<<17) into bucket windows ============
__global__ __launch_bounds__(256) void k_bscatter(const int* __restrict__ src,
                                                  const int* __restrict__ dst,
                                                  int* __restrict__ bCursor,
                                                  int* __restrict__ bucketed, int E, int nb) {
    __shared__ int h[512];
    __shared__ int chunk[512];
    int tid = threadIdx.x;
    for (int i = tid; i < nb; i += 256) h[i] = 0;
    __syncthreads();

    int e0 = blockIdx.x * 2048;
    int myRec[8], myB[8], myRank[8];
#pragma unroll
    for (int k = 0; k < 8; ++k) {
        int e = e0 + k * 256 + tid;
        if (e < E) {
            int d = dst[e];
            myB[k] = d >> 8;
            myRec[k] = src[e] | ((d & 255) << 17);
            myRank[k] = atomicAdd(&h[myB[k]], 1);
        } else {
            myB[k] = -1;
        }
    }
    __syncthreads();
    for (int i = tid; i < nb; i += 256)
        chunk[i] = h[i] ? atomicAdd(&bCursor[i], h[i]) : 0;
    __syncthreads();
#pragma unroll
    for (int k = 0; k < 8; ++k) {
        if (myB[k] >= 0) bucketed[chunk[myB[k]] + myRank[k]] = myRec[k];
    }
}

// ============ per-bucket CSR (512 threads): count -> scan(256) -> pk/dinv + fill ============
// pk[node] = csr_offset | (cnt << 22)   (offset < 3.2M < 2^22, cnt < 1024)
__global__ __launch_bounds__(512) void k_csr(const int* __restrict__ bCursor,
                                             const int* __restrict__ bucketed,
                                             int* __restrict__ pk,
                                             float* __restrict__ dinv, int* __restrict__ csr,
                                             int n) {
    __shared__ int cnt[256];
    __shared__ int s[256];
    __shared__ int cur[256];
    int b = blockIdx.x;
    int node0 = b << 8;
    int tid = threadIdx.x;
    if (tid < 256) cnt[tid] = 0;
    __syncthreads();
    int p0 = b * BCAP, p1 = bCursor[b];
    for (int p = p0 + tid; p < p1; p += 512) {
        int rec = bucketed[p];
        atomicAdd(&cnt[rec >> 17], 1);
    }
    __syncthreads();
    int v = 0;
    if (tid < 256) { v = cnt[tid]; s[tid] = v; }
    __syncthreads();
    for (int off = 1; off < 256; off <<= 1) {
        int t = (tid >= off && tid < 256) ? s[tid - off] : 0;
        __syncthreads();
        if (tid < 256) s[tid] += t;
        __syncthreads();
    }
    if (tid < 256) {
        int myoff = p0 + s[tid] - v;
        cur[tid] = myoff;
        int node = node0 + tid;
        if (node < n) {
            pk[node] = myoff | (v << 22);
            dinv[node] = rsqrtf((float)(v + 1));
        }
    }
    __syncthreads();
    for (int p = p0 + tid; p < p1; p += 512) {
        int rec = bucketed[p];
        int q = atomicAdd(&cur[rec >> 17], 1);
        csr[q] = rec & 0x1FFFF;
    }
}

// ============ MFMA GEMM1: x[N,128](f32) @ W1[128,64] * dinv[r] -> fp8 y[N,64] ============
// 16-row stripe per wave (2x occupancy vs 32-row)
__global__ __launch_bounds__(256) void k_gemm1(const float* __restrict__ x,
                                               const float* __restrict__ W,
                                               const float* __restrict__ dinv,
                                               unsigned char* __restrict__ y, int n) {
    __shared__ unsigned short Wt[HID * 136];
    int tid = threadIdx.x;
    for (int i = tid; i < F_IN * HID; i += 256) {
        int k = i >> 6, nn = i & 63;
        Wt[nn * 136 + k] = f2bf(W[i]);
    }
    __syncthreads();

    int lane = tid & 63;
    int quad = lane >> 4, c = lane & 15;
    int nstripes = (n + 15) >> 4;
    int stripe = blockIdx.x * 4 + (tid >> 6);
    if (stripe >= nstripes) return;
    int row0 = stripe << 4;

    f4 acc[4] = {};
    union { unsigned int u[4]; v8s v; } au;

#pragma unroll
    for (int ks = 0; ks < 4; ++ks) {
        int k0 = ks * 32 + quad * 8;
        int row = row0 + c;
        if (row >= n) row = n - 1;
        const float* xp = x + (size_t)row * F_IN + k0;
        float4 lo = *(const float4*)xp;
        float4 hi = *(const float4*)(xp + 4);
        au.u[0] = pack2(lo.x, lo.y);
        au.u[1] = pack2(lo.z, lo.w);
        au.u[2] = pack2(hi.x, hi.y);
        au.u[3] = pack2(hi.z, hi.w);
        v8s a = au.v;
#pragma unroll
        for (int nt = 0; nt < 4; ++nt) {
            v8s b = *(const v8s*)&Wt[(nt * 16 + c) * 136 + k0];
            acc[nt] = __builtin_amdgcn_mfma_f32_16x16x32_bf16(a, b, acc[nt], 0, 0, 0);
        }
    }

#pragma unroll
    for (int reg = 0; reg < 4; ++reg) {
        int row = row0 + quad * 4 + reg;
        if (row < n) {
            float dd = dinv[row];
#pragma unroll
            for (int nt = 0; nt < 4; ++nt)
                y[(size_t)row * HID + nt * 16 + c] = f2fp8(acc[nt][reg] * dd);
        }
    }
}

// ============ MFMA GEMM2: relu(bf16 h)[N,64] @ W2[64,32] * dinv[r] -> bf16 y[N,32] ============
// 16-row stripe per wave
__global__ __launch_bounds__(256) void k_gemm2(const unsigned short* __restrict__ hb,
                                               const float* __restrict__ W,
                                               const float* __restrict__ dinv,
                                               unsigned short* __restrict__ y, int n) {
    __shared__ unsigned short Wt[CLS * 72];
    int tid = threadIdx.x;
    for (int i = tid; i < HID * CLS; i += 256) {
        int k = i >> 5, nn = i & 31;
        Wt[nn * 72 + k] = f2bf(W[i]);
    }
    __syncthreads();

    int lane = tid & 63;
    int quad = lane >> 4, c = lane & 15;
    int nstripes = (n + 15) >> 4;
    int stripe = blockIdx.x * 4 + (tid >> 6);
    if (stripe >= nstripes) return;
    int row0 = stripe << 4;

    f4 acc[2] = {};
    union { unsigned int u[4]; v8s v; } au;

#pragma unroll
    for (int ks = 0; ks < 2; ++ks) {
        int k0 = ks * 32 + quad * 8;
        int row = row0 + c;
        if (row >= n) row = n - 1;
        uint4 w = *(const uint4*)(hb + (size_t)row * HID + k0);
        au.u[0] = relu2(w.x);
        au.u[1] = relu2(w.y);
        au.u[2] = relu2(w.z);
        au.u[3] = relu2(w.w);
        v8s a = au.v;
#pragma unroll
        for (int nt = 0; nt < 2; ++nt) {
            v8s b = *(const v8s*)&Wt[(nt * 16 + c) * 72 + k0];
            acc[nt] = __builtin_amdgcn_mfma_f32_16x16x32_bf16(a, b, acc[nt], 0, 0, 0);
        }
    }

#pragma unroll
    for (int reg = 0; reg < 4; ++reg) {
        int row = row0 + quad * 4 + reg;
        if (row < n) {
            float dd = dinv[row];
#pragma unroll
            for (int nt = 0; nt < 2; ++nt)
                y[(size_t)row * CLS + nt * 16 + c] = f2bf(acc[nt][reg] * dd);
        }
    }
}

// ============ gather width 64 (fp8 rows, 64B): one node per 16-lane group, 4-way MLP ============
__global__ __launch_bounds__(256) void k_gather64(const int* __restrict__ pk,
                                                  const int* __restrict__ csr,
                                                  const unsigned char* __restrict__ xw8,
                                                  const float* __restrict__ b,
                                                  unsigned short* __restrict__ hb, int n) {
    int node = blockIdx.x * 16 + (threadIdx.x >> 4);
    if (node >= n) return;
    int l = threadIdx.x & 15;    // 4B chunk = cols 4l..4l+3
    unsigned int pv = (unsigned int)pk[node];
    int p0 = pv & 0x3FFFFF;
    int cntv = (int)(pv >> 22);
    int p1 = p0 + cntv;
    float dd = rsqrtf((float)(cntv + 1));
    unsigned int sw = *(const unsigned int*)(xw8 + (size_t)node * HID + l * 4);

    f2 A0 = {0.f, 0.f}, A1 = A0, B0 = A0, B1 = A0, C0 = A0, C1 = A0, D0 = A0, D1 = A0;
    int p = p0;
    for (; p + 3 < p1; p += 4) {
        int s0 = csr[p], s1 = csr[p + 1], s2 = csr[p + 2], s3 = csr[p + 3];
        unsigned int w0 = *(const unsigned int*)(xw8 + (size_t)s0 * HID + l * 4);
        unsigned int w1 = *(const unsigned int*)(xw8 + (size_t)s1 * HID + l * 4);
        unsigned int w2 = *(const unsigned int*)(xw8 + (size_t)s2 * HID + l * 4);
        unsigned int w3 = *(const unsigned int*)(xw8 + (size_t)s3 * HID + l * 4);
        A0 += __builtin_amdgcn_cvt_pk_f32_fp8(w0, false);
        A1 += __builtin_amdgcn_cvt_pk_f32_fp8(w0, true);
        B0 += __builtin_amdgcn_cvt_pk_f32_fp8(w1, false);
        B1 += __builtin_amdgcn_cvt_pk_f32_fp8(w1, true);
        C0 += __builtin_amdgcn_cvt_pk_f32_fp8(w2, false);
        C1 += __builtin_amdgcn_cvt_pk_f32_fp8(w2, true);
        D0 += __builtin_amdgcn_cvt_pk_f32_fp8(w3, false);
        D1 += __builtin_amdgcn_cvt_pk_f32_fp8(w3, true);
    }
    for (; p < p1; ++p) {
        int s = csr[p];
        unsigned int w = *(const unsigned int*)(xw8 + (size_t)s * HID + l * 4);
        A0 += __builtin_amdgcn_cvt_pk_f32_fp8(w, false);
        A1 += __builtin_amdgcn_cvt_pk_f32_fp8(w, true);
    }
    A0 += B0; C0 += D0; A0 += C0;
    A1 += B1; C1 += D1; A1 += C1;

    A0 += __builtin_amdgcn_cvt_pk_f32_fp8(sw, false);
    A1 += __builtin_amdgcn_cvt_pk_f32_fp8(sw, true);
    float4 bb = *(const float4*)(b + l * 4);
    uint2 o;
    o.x = pack2(A0.x * dd + bb.x, A0.y * dd + bb.y);
    o.y = pack2(A1.x * dd + bb.z, A1.y * dd + bb.w);
    *(uint2*)(hb + (size_t)node * HID + l * 4) = o;
}

// ============ gather width 32 (bf16 rows) + log_softmax: group-per-node, 4-way MLP ============
__global__ __launch_bounds__(256) void k_gather32_lsm(const int* __restrict__ pk,
                                                      const int* __restrict__ csr,
                                                      const unsigned short* __restrict__ hwb,
                                                      const float* __restrict__ b,
                                                      float* __restrict__ out, int n) {
    int node = blockIdx.x * 16 + (threadIdx.x >> 4);
    if (node >= n) return;
    int l = threadIdx.x & 15;    // cols 2l, 2l+1
    unsigned int pv = (unsigned int)pk[node];
    int p0 = pv & 0x3FFFFF;
    int cntv = (int)(pv >> 22);
    int p1 = p0 + cntv;
    float dd = rsqrtf((float)(cntv + 1));
    unsigned int sw = *(const unsigned int*)(hwb + (size_t)node * CLS + l * 2);

    float A0 = 0.f, A1 = 0.f, B0 = 0.f, B1 = 0.f, C0 = 0.f, C1 = 0.f, D0 = 0.f, D1 = 0.f;
    int p = p0;
    for (; p + 3 < p1; p += 4) {
        int s0 = csr[p], s1 = csr[p + 1], s2 = csr[p + 2], s3 = csr[p + 3];
        unsigned int w0 = *(const unsigned int*)(hwb + (size_t)s0 * CLS + l * 2);
        unsigned int w1 = *(const unsigned int*)(hwb + (size_t)s1 * CLS + l * 2);
        unsigned int w2 = *(const unsigned int*)(hwb + (size_t)s2 * CLS + l * 2);
        unsigned int w3 = *(const unsigned int*)(hwb + (size_t)s3 * CLS + l * 2);
        A0 += bflo(w0); A1 += bfhi(w0);
        B0 += bflo(w1); B1 += bfhi(w1);
        C0 += bflo(w2); C1 += bfhi(w2);
        D0 += bflo(w3); D1 += bfhi(w3);
    }
    for (; p < p1; ++p) {
        int s = csr[p];
        unsigned int w = *(const unsigned int*)(hwb + (size_t)s * CLS + l * 2);
        A0 += bflo(w); A1 += bfhi(w);
    }
    A0 += B0; C0 += D0; A0 += C0;
    A1 += B1; C1 += D1; A1 += C1;

    float v0 = (A0 + bflo(sw)) * dd + b[l * 2];
    float v1 = (A1 + bfhi(sw)) * dd + b[l * 2 + 1];

    float m = fmaxf(v0, v1);
    m = fmaxf(m, __shfl_xor(m, 1));
    m = fmaxf(m, __shfl_xor(m, 2));
    m = fmaxf(m, __shfl_xor(m, 4));
    m = fmaxf(m, __shfl_xor(m, 8));
    float s = __expf(v0 - m) + __expf(v1 - m);
    s += __shfl_xor(s, 1);
    s += __shfl_xor(s, 2);
    s += __shfl_xor(s, 4);
    s += __shfl_xor(s, 8);
    float ls = m + __logf(s);
    float2 o;
    o.x = v0 - ls;
    o.y = v1 - ls;
    *(float2*)(out + (size_t)node * CLS + l * 2) = o;
}

extern "C" void kernel_launch(void* const* d_in, const int* in_sizes, int n_in,
                              void* d_out, int out_size, void* d_ws, size_t ws_size,
                              hipStream_t stream) {
    const float* x  = (const float*)d_in[0];
    const int* edge = (const int*)d_in[1];
    const float* W1 = (const float*)d_in[2];
    const float* b1 = (const float*)d_in[3];
    const float* W2 = (const float*)d_in[4];
    const float* b2 = (const float*)d_in[5];
    float* out = (float*)d_out;

    int N = in_sizes[0] / F_IN;
    int E = in_sizes[1] / 2;
    const int* src = edge;
    const int* dst = edge + E;
    int NB = (N + 255) >> 8;   // 391 buckets

    // workspace layout
    float* dinv    = (float*)d_ws;                        // N f32 (gemm epilogues)
    int* pk        = (int*)(dinv + N);                    // N (off | cnt<<22)
    int* bCursor   = pk + N;                              // 512
    int* csr       = bCursor + 512;                       // NB*BCAP (windowed)
    int* bucketed  = csr + (size_t)NB * BCAP;             // NB*BCAP (windowed)
    unsigned char* bufA = (unsigned char*)(bucketed + (size_t)NB * BCAP);  // N*64 B fp8 xw, later bf16 hw
    unsigned short* bufB = (unsigned short*)(bufA + (size_t)N * HID);      // N*64 bf16 h1

    // ---- bucketed CSR build ----
    k_init<<<1, 512, 0, stream>>>(bCursor, NB);
    k_bscatter<<<(E + 2047) / 2048, 256, 0, stream>>>(src, dst, bCursor, bucketed, E, NB);
    k_csr<<<NB, 512, 0, stream>>>(bCursor, bucketed, pk, dinv, csr, N);

    int nstripes16 = (N + 15) >> 4;
    int gemmBlocks = (nstripes16 + 3) / 4;
    int gatherBlocks = (N + 15) / 16;

    // ---- layer 1 (fp8 xw table) ----
    k_gemm1<<<gemmBlocks, 256, 0, stream>>>(x, W1, dinv, bufA, N);
    k_gather64<<<gatherBlocks, 256, 0, stream>>>(pk, csr, bufA, b1, bufB, N);

    // ---- layer 2 (bf16 hw table, aliases bufA) ----
    k_gemm2<<<gemmBlocks, 256, 0, stream>>>(bufB, W2, dinv, (unsigned short*)bufA, N);
    k_gather32_lsm<<<gatherBlocks, 256, 0, stream>>>(pk, csr, (unsigned short*)bufA, b2, out, N);
}